// Round 13
// baseline (198.993 us; speedup 1.0000x reference)
//
#include <hip/hip_runtime.h>
#include <hip/hip_bf16.h>
#include <hip/hip_fp16.h>
#include <math.h>

#define N_NODES 100000
#define N_EDGES 1600000
#define F_IN 16
#define HDIM 64
#define E_DIM 9
#define NEG 0.2f

#define NSLICE 8
#define SLICE_W 12500                     // dst-slice width (100000/8)
#define NSTRIPE 32                        // tail-counter striping (R2)
#define STRIPE_CAP 7680                   // per-(slice,stripe) region
#define NSUB 128                          // sub-bins per slice
#define SUBW 98                           // nodes per sub-bin (128*98=12544>=12500)
#define SUB_CAP 2048                      // entries per sub-bin; mean 1568 + 12 sigma
#define K3_CHUNK 1920                     // STRIPE_CAP/4
#define EPB 512                           // edges per k_edge_pre block
#define NCTR (NSLICE * NSTRIPE * 16 + NSLICE * NSUB * 16)  // 20480 u32 counters

typedef unsigned long long ull;
typedef long long ll;

__device__ __forceinline__ void bf2(unsigned u, float& lo, float& hi) {
  lo = __uint_as_float(u << 16);
  hi = __uint_as_float(u & 0xFFFF0000u);
}

__device__ __forceinline__ unsigned bfpack(float a, float b) {
  unsigned ua = __float_as_uint(a); ua += 0x7fffu + ((ua >> 16) & 1u);
  unsigned ub = __float_as_uint(b); ub += 0x7fffu + ((ub >> 16) & 1u);
  return (ua >> 16) | (ub & 0xFFFF0000u);
}

__device__ __forceinline__ unsigned bf16rne(float a) {
  unsigned u = __float_as_uint(a);
  u += 0x7fffu + ((u >> 16) & 1u);
  return (u >> 16) & 0xFFFFu;
}

// ---- K1 (k_node_h): one THREAD per node. Folds in k_we (block 0 computes
// w_e[0..8]; every block derives wa_src/wa_dst from W in-LDS) and the counter
// memset (first 20480 threads zero gcount+sub_tail). ----
__global__ __launch_bounds__(256) void k_node_h(
    const float* __restrict__ x, const float* __restrict__ W,
    const float* __restrict__ att_src, const float* __restrict__ att_dst,
    const float* __restrict__ W_edge, const float* __restrict__ att_edge,
    float* __restrict__ w_e, unsigned* __restrict__ gcount,
    __hip_bfloat16* __restrict__ xbf, float* __restrict__ a_src,
    float* __restrict__ a_dst) {
  __shared__ float swa[32];
  int t = threadIdx.x;
  int gid = blockIdx.x * 256 + t;
  if (gid < NCTR) gcount[gid] = 0;          // counters zeroed before k_edge_pre/k_sub
  if (t < 32) {
    int k = t & 15;
    const float* av = (t < 16) ? att_src : att_dst;
    float s = 0.f;
    for (int hh = 0; hh < HDIM; ++hh) s += W[k * HDIM + hh] * av[hh];
    swa[t] = s;
  }
  if (blockIdx.x == 0 && t >= 64 && t < 64 + E_DIM) {
    int d = t - 64;
    float s = 0.f;
    for (int hh = 0; hh < HDIM; ++hh) s += W_edge[d * HDIM + hh] * att_edge[hh];
    w_e[d] = s;
  }
  __syncthreads();
  int node = gid;
  if (node >= N_NODES) return;
  const float4* xp = (const float4*)(x + (size_t)node * F_IN);
  float4 v0 = xp[0], v1 = xp[1], v2 = xp[2], v3 = xp[3];
  float xv[F_IN] = {v0.x, v0.y, v0.z, v0.w, v1.x, v1.y, v1.z, v1.w,
                    v2.x, v2.y, v2.z, v2.w, v3.x, v3.y, v3.z, v3.w};
  float s1 = 0.f, s2 = 0.f;
#pragma unroll
  for (int k = 0; k < F_IN; ++k) {
    s1 += xv[k] * swa[k];
    s2 += xv[k] * swa[16 + k];
  }
  a_src[node] = s1;
  a_dst[node] = s2;
  uint4 p0, p1;
  p0.x = bfpack(xv[0], xv[1]);   p0.y = bfpack(xv[2], xv[3]);
  p0.z = bfpack(xv[4], xv[5]);   p0.w = bfpack(xv[6], xv[7]);
  p1.x = bfpack(xv[8], xv[9]);   p1.y = bfpack(xv[10], xv[11]);
  p1.z = bfpack(xv[12], xv[13]); p1.w = bfpack(xv[14], xv[15]);
  uint4* op = (uint4*)(xbf + (size_t)node * F_IN);
  op[0] = p0;
  op[1] = p1;
}

// ---- K2 (k_edge_pre) R12: full logit math folded in (moved from k_sub —
// this kernel is stream-bound with MLP slack, so the a_src/a_dst L2 gathers
// and exp hide under the 70 MB stream; k_sub becomes a pure permute).
// Entry = {dloc:14 | ee(bf16):16 | ae(f16):16 | src:17} = 63 bits.
// nt store OK: contiguous runs. ----
__global__ __launch_bounds__(256) void k_edge_pre(
    const float* __restrict__ ea, const int* __restrict__ ei,
    const float* __restrict__ w_e, const float* __restrict__ a_src,
    const float* __restrict__ a_dst, ull* __restrict__ sstream,
    unsigned* __restrict__ gcount) {
  __shared__ unsigned wcnt[4][NSLICE];
  __shared__ unsigned woff[4][NSLICE];
  __shared__ unsigned gbase[NSLICE];
  int t = threadIdx.x;
  int wave = t >> 6, lane = t & 63;
  unsigned stripe = blockIdx.x & (NSTRIPE - 1);
  size_t tile = (size_t)blockIdx.x * (EPB * E_DIM);
  int e0 = blockIdx.x * EPB + t;
  int e1 = e0 + 256;
  int s0 = __builtin_nontemporal_load(ei + e0);
  int s1 = __builtin_nontemporal_load(ei + e1);
  int d0 = __builtin_nontemporal_load(ei + N_EDGES + e0);
  int d1 = __builtin_nontemporal_load(ei + N_EDGES + e1);
  // issue the 4 L2 gathers early (hide under the attr stream below)
  float as0 = a_src[s0], as1 = a_src[s1];
  float ad0 = a_dst[d0], ad1 = a_dst[d1];
  // direct per-edge attr loads (all 18 issued before the dots for MLP)
  float r0[E_DIM], r1[E_DIM];
  const float* p0 = ea + tile + (size_t)t * E_DIM;
  const float* p1 = ea + tile + (size_t)(t + 256) * E_DIM;
#pragma unroll
  for (int k = 0; k < E_DIM; ++k) r0[k] = p0[k];
#pragma unroll
  for (int k = 0; k < E_DIM; ++k) r1[k] = p1[k];
  float ae0 = 0.f, ae1 = 0.f;
#pragma unroll
  for (int k = 0; k < E_DIM; ++k) {
    float w = w_e[k];                       // uniform -> scalar load
    ae0 += r0[k] * w;
    ae1 += r1[k] * w;
  }
  // logit -> leaky -> exp (shift-invariant softmax), here not in k_sub
  float al0 = as0 + ad0 + ae0; al0 = al0 >= 0.f ? al0 : NEG * al0;
  float al1 = as1 + ad1 + ae1; al1 = al1 >= 0.f ? al1 : NEG * al1;
  unsigned ee0 = bf16rne(expf(al0));
  unsigned ee1 = bf16rne(expf(al1));
  unsigned ah0 = (unsigned)__half_as_ushort(__float2half(ae0));
  unsigned ah1 = (unsigned)__half_as_ushort(__float2half(ae1));
  unsigned slice0 = (unsigned)d0 / SLICE_W, slice1 = (unsigned)d1 / SLICE_W;
  unsigned dloc0 = (unsigned)d0 - slice0 * SLICE_W;
  unsigned dloc1 = (unsigned)d1 - slice1 * SLICE_W;
  ull entry0 = ((ull)dloc0 << 50) | ((ull)ee0 << 34) | ((ull)ah0 << 18) |
               (ull)(unsigned)s0;
  ull entry1 = ((ull)dloc1 << 50) | ((ull)ee1 << 34) | ((ull)ah1 << 18) |
               (ull)(unsigned)s1;
  // wave-level ranking via ballot (both edges per iteration)
  ull lt = (lane == 63) ? 0x7FFFFFFFFFFFFFFFull : ((1ull << lane) - 1ull);
  unsigned rank0 = 0, rank1 = 0;
#pragma unroll
  for (int si = 0; si < NSLICE; ++si) {
    ull m0 = __ballot(slice0 == (unsigned)si);
    ull m1 = __ballot(slice1 == (unsigned)si);
    unsigned c0 = (unsigned)__popcll(m0);
    if (slice0 == (unsigned)si) rank0 = (unsigned)__popcll(m0 & lt);
    if (slice1 == (unsigned)si) rank1 = c0 + (unsigned)__popcll(m1 & lt);
    if (lane == 0) wcnt[wave][si] = c0 + (unsigned)__popcll(m1);
  }
  __syncthreads();
  if (t < NSLICE) {
    unsigned a = 0;
#pragma unroll
    for (int w = 0; w < 4; ++w) { woff[w][t] = a; a += wcnt[w][t]; }
    gbase[t] = atomicAdd(gcount + ((unsigned)t * NSTRIPE + stripe) * 16, a);
  }
  __syncthreads();
  unsigned off0 = gbase[slice0] + woff[wave][slice0] + rank0;
  if (off0 < STRIPE_CAP)
    __builtin_nontemporal_store(
        entry0, sstream + (size_t)(slice0 * NSTRIPE + stripe) * STRIPE_CAP + off0);
  unsigned off1 = gbase[slice1] + woff[wave][slice1] + rank1;
  if (off1 < STRIPE_CAP)
    __builtin_nontemporal_store(
        entry1, sstream + (size_t)(slice1 * NSTRIPE + stripe) * STRIPE_CAP + off1);
}

// ---- K3 (k_sub) R12: pure permute now — no gathers, no exp (moved to
// k_edge_pre). Stream in, LDS histogram, scatter out. Out entry =
// {dlocs:7 | ee:16 | ae:16 | src:17}. Scatter store PLAIN (R7 lesson: nt on
// 8B scatters = 6x write amplification). ----
__global__ __launch_bounds__(512) void k_sub(
    const ull* __restrict__ sstream, const unsigned* __restrict__ gcount,
    ull* __restrict__ sub_stream, unsigned* __restrict__ sub_tail) {
  __shared__ unsigned hist[NSUB];
  __shared__ unsigned gb[NSUB];
  int t = threadIdx.x;
  int b = blockIdx.x;
  int slice = b & 7;
  int stripe = (b >> 3) & (NSTRIPE - 1);
  int chunk = b >> 8;                       // 0..3
  unsigned n = gcount[(slice * NSTRIPE + stripe) * 16];
  if (n > STRIPE_CAP) n = STRIPE_CAP;
  const ull* rb = sstream + (size_t)(slice * NSTRIPE + stripe) * STRIPE_CAP;
  unsigned start = (unsigned)chunk * K3_CHUNK;
  unsigned end = n < start + K3_CHUNK ? n : start + K3_CHUNK;
  if (t < NSUB) hist[t] = 0;
  __syncthreads();
  ull ent[4];
  unsigned bn[4];
  bool val[4];
#pragma unroll
  for (int u = 0; u < 4; ++u) {
    unsigned i = start + (unsigned)u * 512 + (unsigned)t;
    val[u] = (i < end);
    ent[u] = val[u] ? __builtin_nontemporal_load(rb + i) : 0ull;
  }
#pragma unroll
  for (int u = 0; u < 4; ++u) {
    unsigned dloc = (unsigned)(ent[u] >> 50);
    bn[u] = dloc / SUBW;
    if (val[u]) atomicAdd(&hist[bn[u]], 1u);
  }
  __syncthreads();
  if (t < NSUB && hist[t]) gb[t] = atomicAdd(sub_tail + ((slice * NSUB + t) * 16), hist[t]);
  __syncthreads();
  if (t < NSUB) hist[t] = 0;                // reuse as per-bin cursor
  __syncthreads();
#pragma unroll
  for (int u = 0; u < 4; ++u) {
    if (!val[u]) continue;
    unsigned src = (unsigned)(ent[u] & 0x1FFFFu);
    unsigned aeh = (unsigned)((ent[u] >> 18) & 0xFFFFu);
    unsigned ee16 = (unsigned)((ent[u] >> 34) & 0xFFFFu);
    unsigned dloc = (unsigned)(ent[u] >> 50);
    unsigned dlocs = dloc - bn[u] * SUBW;   // 0..97
    ull e2 = ((ull)dlocs << 57) | ((ull)ee16 << 41) | ((ull)aeh << 25) | (ull)src;
    unsigned r = atomicAdd(&hist[bn[u]], 1u);
    unsigned pos = gb[bn[u]] + r;
    if (pos < SUB_CAP)
      sub_stream[(size_t)(slice * NSUB + bn[u]) * SUB_CAP + pos] = e2;
  }
}

// ---- K4 (k_acc): Phase A in-LDS counting sort (1 LDS atomic/entry). Phase B
// 4 lanes/node, single-entry loop. R12: entry fields at new bit positions
// {dlocs:7@57 | ee:16@41 | ae:16@25 | src:17@0}. ----
__global__ __launch_bounds__(512) void k_acc(
    const ull* __restrict__ sub_stream, const unsigned* __restrict__ sub_tail,
    const __hip_bfloat16* __restrict__ xbf, const float* __restrict__ W,
    const float* __restrict__ a_src, const float* __restrict__ a_dst,
    const float* __restrict__ bias, const float* __restrict__ lin_w,
    float* __restrict__ s_node) {
  __shared__ ull sorted[SUB_CAP];           // 16 KB
  __shared__ unsigned hist[NSUB];
  __shared__ unsigned pref[NSUB];
  __shared__ unsigned w0tot;
  __shared__ float sW[F_IN * HDIM];
  __shared__ float sb[HDIM], sl[HDIM];
  int t = threadIdx.x;
  int slice = blockIdx.x & 7;
  int bin = blockIdx.x >> 3;
  int nbase = slice * SLICE_W + bin * SUBW;
  int nnodes = SLICE_W - bin * SUBW; if (nnodes > SUBW) nnodes = SUBW;   // 98 or 54
  if (t < NSUB) hist[t] = 0;
  for (int i = t; i < F_IN * HDIM; i += 512) sW[i] = W[i];
  if (t < HDIM) { sb[t] = bias[t]; sl[t] = lin_w[t]; }
  __syncthreads();
  unsigned n = sub_tail[(slice * NSUB + bin) * 16];
  if (n > SUB_CAP) n = SUB_CAP;
  const ull* sp = sub_stream + (size_t)(slice * NSUB + bin) * SUB_CAP;
  // Phase A: count + rank
  ull ent[4];
  unsigned dl4[4], rk[4];
  bool val[4];
#pragma unroll
  for (int u = 0; u < 4; ++u) {
    unsigned i = (unsigned)u * 512 + (unsigned)t;
    val[u] = (i < n);
    ent[u] = val[u] ? sp[i] : 0ull;
  }
#pragma unroll
  for (int u = 0; u < 4; ++u) {
    dl4[u] = (unsigned)(ent[u] >> 57);
    if (val[u]) rk[u] = atomicAdd(&hist[dl4[u]], 1u);
  }
  __syncthreads();
  // exclusive prefix over 128 bins (waves 0,1 via shfl_up)
  if (t < NSUB) {
    unsigned v = hist[t];
    unsigned sc = v;
#pragma unroll
    for (int off = 1; off < 64; off <<= 1) {
      unsigned o = __shfl_up(sc, off);
      if ((t & 63) >= off) sc += o;
    }
    pref[t] = sc - v;                       // exclusive within wave
    if (t == 63) w0tot = sc;                // total of bins 0..63
  }
  __syncthreads();
  if (t >= 64 && t < NSUB) pref[t] += w0tot;
  __syncthreads();
  // scatter to sorted order
#pragma unroll
  for (int u = 0; u < 4; ++u)
    if (val[u]) sorted[pref[dl4[u]] + rk[u]] = ent[u];
  __syncthreads();
  // Phase B: 4 lanes/node, 128 groups (nnodes <= 98 -> one pass)
  int g = t >> 2, il = t & 3;
  if (g < nnodes) {
    int nl = g;
    int node = nbase + nl;
    unsigned start = pref[nl];
    unsigned cnt = hist[nl];
    float acc[F_IN];
#pragma unroll
    for (int j = 0; j < F_IN; ++j) acc[j] = 0.f;
    float denom = 0.f, sumae = 0.f;
    for (unsigned k = il; k < cnt; k += 4) {
      ull e2 = sorted[start + k];
      unsigned src = (unsigned)(e2 & 0x1FFFFu);
      float ae = __half2float(__ushort_as_half((unsigned short)((e2 >> 25) & 0xFFFFu)));
      float ee = __uint_as_float(((unsigned)((e2 >> 41) & 0xFFFFu)) << 16);
      const uint4* xp = (const uint4*)(xbf + (size_t)src * F_IN);
      uint4 xa = xp[0], xb = xp[1];
      denom += ee;
      sumae += ae;
      float f0, f1;
      bf2(xa.x, f0, f1); acc[0] += ee * f0;  acc[1] += ee * f1;
      bf2(xa.y, f0, f1); acc[2] += ee * f0;  acc[3] += ee * f1;
      bf2(xa.z, f0, f1); acc[4] += ee * f0;  acc[5] += ee * f1;
      bf2(xa.w, f0, f1); acc[6] += ee * f0;  acc[7] += ee * f1;
      bf2(xb.x, f0, f1); acc[8] += ee * f0;  acc[9] += ee * f1;
      bf2(xb.y, f0, f1); acc[10] += ee * f0; acc[11] += ee * f1;
      bf2(xb.z, f0, f1); acc[12] += ee * f0; acc[13] += ee * f1;
      bf2(xb.w, f0, f1); acc[14] += ee * f0; acc[15] += ee * f1;
    }
    // reduce over the 4 lanes of this group (all lanes end with full sums)
#pragma unroll
    for (int off = 2; off > 0; off >>= 1) {
      denom += __shfl_xor(denom, off, 4);
      sumae += __shfl_xor(sumae, off, 4);
#pragma unroll
      for (int j = 0; j < F_IN; ++j) acc[j] += __shfl_xor(acc[j], off, 4);
    }
    // self-loop (fill_value='mean'): logit uses mean of incident a_e
    float all = a_src[node] + a_dst[node] + sumae / fmaxf((float)cnt, 1.f);
    all = all >= 0.f ? all : NEG * all;
    float eel = expf(all);
    denom += eel;
    {
      const uint4* xp = (const uint4*)(xbf + (size_t)node * F_IN);
      uint4 xa = xp[0], xb = xp[1];
      float f0, f1;
      bf2(xa.x, f0, f1); acc[0] += eel * f0;  acc[1] += eel * f1;
      bf2(xa.y, f0, f1); acc[2] += eel * f0;  acc[3] += eel * f1;
      bf2(xa.z, f0, f1); acc[4] += eel * f0;  acc[5] += eel * f1;
      bf2(xa.w, f0, f1); acc[6] += eel * f0;  acc[7] += eel * f1;
      bf2(xb.x, f0, f1); acc[8] += eel * f0;  acc[9] += eel * f1;
      bf2(xb.y, f0, f1); acc[10] += eel * f0; acc[11] += eel * f1;
      bf2(xb.z, f0, f1); acc[12] += eel * f0; acc[13] += eel * f1;
      bf2(xb.w, f0, f1); acc[14] += eel * f0; acc[15] += eel * f1;
    }
    float inv = 1.f / (denom + 1e-16f);
    // GEMV: lane il handles h = il + 4*stp, stp = 0..15
    float o = 0.f;
#pragma unroll
    for (int stp = 0; stp < 16; ++stp) {
      int h = il + stp * 4;
      float oh = 0.f;
#pragma unroll
      for (int j = 0; j < F_IN; ++j) oh += acc[j] * sW[j * HDIM + h];
      o += fmaxf(oh * inv + sb[h], 0.f) * sl[h];
    }
#pragma unroll
    for (int off = 2; off > 0; off >>= 1) o += __shfl_xor(o, off, 4);
    if (il == 0) s_node[node] = o;
  }
}

// ---- K5 (k_out): 4 edges/thread via int4/float4 — 8 independent s_node
// gathers in flight. ----
__global__ __launch_bounds__(256) void k_out(
    const int* __restrict__ ei, const float* __restrict__ s_node,
    const float* __restrict__ lin_b, float* __restrict__ out) {
  int e = (blockIdx.x * 256 + threadIdx.x) * 4;
  if (e >= N_EDGES) return;
  int4 ss = *(const int4*)(ei + e);
  int4 dd = *(const int4*)(ei + N_EDGES + e);
  float lb = lin_b[0];
  float s0 = s_node[ss.x], s1 = s_node[ss.y], s2 = s_node[ss.z], s3 = s_node[ss.w];
  float t0 = s_node[dd.x], t1 = s_node[dd.y], t2 = s_node[dd.z], t3 = s_node[dd.w];
  float4 r;
  r.x = 1.f / (1.f + expf(-(0.5f * (s0 + t0) + lb)));
  r.y = 1.f / (1.f + expf(-(0.5f * (s1 + t1) + lb)));
  r.z = 1.f / (1.f + expf(-(0.5f * (s2 + t2) + lb)));
  r.w = 1.f / (1.f + expf(-(0.5f * (s3 + t3) + lb)));
  *(float4*)(out + e) = r;
}

extern "C" void kernel_launch(void* const* d_in, const int* in_sizes, int n_in,
                              void* d_out, int out_size, void* d_ws, size_t ws_size,
                              hipStream_t stream) {
  const float* x        = (const float*)d_in[0];
  const float* edge_attr= (const float*)d_in[1];
  const float* W        = (const float*)d_in[2];
  const float* W_edge   = (const float*)d_in[3];
  const float* att_src  = (const float*)d_in[4];
  const float* att_dst  = (const float*)d_in[5];
  const float* att_edge = (const float*)d_in[6];
  const float* bias     = (const float*)d_in[7];
  const float* lin_w    = (const float*)d_in[8];
  const float* lin_b    = (const float*)d_in[9];
  const int*   ei       = (const int*)d_in[10];
  float* out = (float*)d_out;

  // workspace layout (16-B alignment preserved)
  char* base = (char*)d_ws;
  __hip_bfloat16* xbf = (__hip_bfloat16*)base;                      // 3.2 MB
  ull* sstream = (ull*)(base + (size_t)N_NODES * F_IN * 2);         // 256*7680*8 = 15.73 MB
  ull* sub_stream = sstream + (size_t)NSLICE * NSTRIPE * STRIPE_CAP; // 1024*2048*8 = 16.78 MB
  unsigned* gcount = (unsigned*)(sub_stream + (size_t)NSLICE * NSUB * SUB_CAP); // 16 KB (zeroed by k_node_h)
  unsigned* sub_tail = gcount + NSLICE * NSTRIPE * 16;              // 64 KB (zeroed by k_node_h)
  float* a_src  = (float*)(sub_tail + NSLICE * NSUB * 16);          // N
  float* a_dst  = a_src + N_NODES;                                  // N
  float* s_node = a_dst + N_NODES;                                  // N
  float* w_e    = s_node + N_NODES;                                 // 16
  // total ~ 37 MB

  int nb_node   = (N_NODES + 255) / 256;    // 391
  int nb_edge_p = N_EDGES / EPB;            // 3125, exact
  int nb_sub    = NSLICE * NSTRIPE * 4;     // 1024
  int nb_acc    = NSLICE * NSUB;            // 1024
  int nb_out    = (N_EDGES / 4 + 255) / 256; // 1563

  k_node_h  <<<nb_node, 256, 0, stream>>>(x, W, att_src, att_dst, W_edge,
                                          att_edge, w_e, gcount, xbf, a_src,
                                          a_dst);
  k_edge_pre<<<nb_edge_p, 256, 0, stream>>>(edge_attr, ei, w_e, a_src, a_dst,
                                            sstream, gcount);
  k_sub     <<<nb_sub, 512, 0, stream>>>(sstream, gcount, sub_stream, sub_tail);
  k_acc     <<<nb_acc, 512, 0, stream>>>(sub_stream, sub_tail, xbf, W,
                                         a_src, a_dst, bias, lin_w, s_node);
  k_out     <<<nb_out, 256, 0, stream>>>(ei, s_node, lin_b, out);
}

// Round 14
// 188.780 us; speedup vs baseline: 1.0541x; 1.0541x over previous
//
#include <hip/hip_runtime.h>
#include <hip/hip_bf16.h>
#include <hip/hip_fp16.h>
#include <math.h>

#define N_NODES 100000
#define N_EDGES 1600000
#define F_IN 16
#define HDIM 64
#define E_DIM 9
#define NEG 0.2f

#define NSLICE 8
#define SLICE_W 12500                     // dst-slice width (100000/8)
#define NSTRIPE 32                        // tail-counter striping (R2)
#define STRIPE_CAP 7680                   // per-(slice,stripe) region
#define NSUB 128                          // sub-bins per slice
#define SUBW 98                           // nodes per sub-bin (128*98=12544>=12500)
#define SUB_CAP 2048                      // entries per sub-bin; mean 1568 + 12 sigma
#define K3_CHUNK 1920                     // STRIPE_CAP/4
#define EPB 512                           // edges per k_edge_pre block
#define NCTR (NSLICE * NSTRIPE * 16 + NSLICE * NSUB * 16)  // 20480 u32 counters

typedef unsigned long long ull;
typedef long long ll;

__device__ __forceinline__ void bf2(unsigned u, float& lo, float& hi) {
  lo = __uint_as_float(u << 16);
  hi = __uint_as_float(u & 0xFFFF0000u);
}

__device__ __forceinline__ unsigned bfpack(float a, float b) {
  unsigned ua = __float_as_uint(a); ua += 0x7fffu + ((ua >> 16) & 1u);
  unsigned ub = __float_as_uint(b); ub += 0x7fffu + ((ub >> 16) & 1u);
  return (ua >> 16) | (ub & 0xFFFF0000u);
}

// ---- K1 (k_node_h): one THREAD per node. Folds in k_we (block 0 computes
// w_e[0..8]; every block derives wa_src/wa_dst from W in-LDS) and the counter
// memset (first 20480 threads zero gcount+sub_tail). ----
__global__ __launch_bounds__(256) void k_node_h(
    const float* __restrict__ x, const float* __restrict__ W,
    const float* __restrict__ att_src, const float* __restrict__ att_dst,
    const float* __restrict__ W_edge, const float* __restrict__ att_edge,
    float* __restrict__ w_e, unsigned* __restrict__ gcount,
    __hip_bfloat16* __restrict__ xbf, float* __restrict__ a_src,
    float* __restrict__ a_dst) {
  __shared__ float swa[32];
  int t = threadIdx.x;
  int gid = blockIdx.x * 256 + t;
  if (gid < NCTR) gcount[gid] = 0;          // counters zeroed before k_edge_pre/k_sub
  if (t < 32) {
    int k = t & 15;
    const float* av = (t < 16) ? att_src : att_dst;
    float s = 0.f;
    for (int hh = 0; hh < HDIM; ++hh) s += W[k * HDIM + hh] * av[hh];
    swa[t] = s;
  }
  if (blockIdx.x == 0 && t >= 64 && t < 64 + E_DIM) {
    int d = t - 64;
    float s = 0.f;
    for (int hh = 0; hh < HDIM; ++hh) s += W_edge[d * HDIM + hh] * att_edge[hh];
    w_e[d] = s;
  }
  __syncthreads();
  int node = gid;
  if (node >= N_NODES) return;
  const float4* xp = (const float4*)(x + (size_t)node * F_IN);
  float4 v0 = xp[0], v1 = xp[1], v2 = xp[2], v3 = xp[3];
  float xv[F_IN] = {v0.x, v0.y, v0.z, v0.w, v1.x, v1.y, v1.z, v1.w,
                    v2.x, v2.y, v2.z, v2.w, v3.x, v3.y, v3.z, v3.w};
  float s1 = 0.f, s2 = 0.f;
#pragma unroll
  for (int k = 0; k < F_IN; ++k) {
    s1 += xv[k] * swa[k];
    s2 += xv[k] * swa[16 + k];
  }
  a_src[node] = s1;
  a_dst[node] = s2;
  uint4 p0, p1;
  p0.x = bfpack(xv[0], xv[1]);   p0.y = bfpack(xv[2], xv[3]);
  p0.z = bfpack(xv[4], xv[5]);   p0.w = bfpack(xv[6], xv[7]);
  p1.x = bfpack(xv[8], xv[9]);   p1.y = bfpack(xv[10], xv[11]);
  p1.z = bfpack(xv[12], xv[13]); p1.w = bfpack(xv[14], xv[15]);
  uint4* op = (uint4*)(xbf + (size_t)node * F_IN);
  op[0] = p0;
  op[1] = p1;
}

// ---- K2 (k_edge_pre): 2 edges/thread, direct attr loads (no LDS staging —
// R11: it was an identity copy; wave reads a dense 2.3 KB region, L1 covers
// re-touches), w_e via uniform scalar loads. Ballot ranking; nt store OK:
// contiguous runs. Logit math stays DOWNSTREAM (R12 lesson: gathers before a
// wave-synchronous ballot stall all 64 lanes on one straggler). ----
__global__ __launch_bounds__(256) void k_edge_pre(
    const float* __restrict__ ea, const int* __restrict__ ei,
    const float* __restrict__ w_e, ull* __restrict__ sstream,
    unsigned* __restrict__ gcount) {
  __shared__ unsigned wcnt[4][NSLICE];
  __shared__ unsigned woff[4][NSLICE];
  __shared__ unsigned gbase[NSLICE];
  int t = threadIdx.x;
  int wave = t >> 6, lane = t & 63;
  unsigned stripe = blockIdx.x & (NSTRIPE - 1);
  size_t tile = (size_t)blockIdx.x * (EPB * E_DIM);
  int e0 = blockIdx.x * EPB + t;
  int e1 = e0 + 256;
  int s0 = __builtin_nontemporal_load(ei + e0);
  int s1 = __builtin_nontemporal_load(ei + e1);
  int d0 = __builtin_nontemporal_load(ei + N_EDGES + e0);
  int d1 = __builtin_nontemporal_load(ei + N_EDGES + e1);
  // direct per-edge attr loads (issue all 18 before the dots for MLP)
  float r0[E_DIM], r1[E_DIM];
  const float* p0 = ea + tile + (size_t)t * E_DIM;
  const float* p1 = ea + tile + (size_t)(t + 256) * E_DIM;
#pragma unroll
  for (int k = 0; k < E_DIM; ++k) r0[k] = p0[k];
#pragma unroll
  for (int k = 0; k < E_DIM; ++k) r1[k] = p1[k];
  float ae0 = 0.f, ae1 = 0.f;
#pragma unroll
  for (int k = 0; k < E_DIM; ++k) {
    float w = w_e[k];                       // uniform -> scalar load
    ae0 += r0[k] * w;
    ae1 += r1[k] * w;
  }
  unsigned slice0 = (unsigned)d0 / SLICE_W, slice1 = (unsigned)d1 / SLICE_W;
  unsigned dloc0 = (unsigned)d0 - slice0 * SLICE_W;
  unsigned dloc1 = (unsigned)d1 - slice1 * SLICE_W;
  ull entry0 = ((ull)dloc0 << 48) |
               ((ull)(unsigned)__half_as_ushort(__float2half(ae0)) << 32) |
               (ull)(unsigned)s0;
  ull entry1 = ((ull)dloc1 << 48) |
               ((ull)(unsigned)__half_as_ushort(__float2half(ae1)) << 32) |
               (ull)(unsigned)s1;
  // wave-level ranking via ballot (both edges per iteration)
  ull lt = (lane == 63) ? 0x7FFFFFFFFFFFFFFFull : ((1ull << lane) - 1ull);
  unsigned rank0 = 0, rank1 = 0;
#pragma unroll
  for (int si = 0; si < NSLICE; ++si) {
    ull m0 = __ballot(slice0 == (unsigned)si);
    ull m1 = __ballot(slice1 == (unsigned)si);
    unsigned c0 = (unsigned)__popcll(m0);
    if (slice0 == (unsigned)si) rank0 = (unsigned)__popcll(m0 & lt);
    if (slice1 == (unsigned)si) rank1 = c0 + (unsigned)__popcll(m1 & lt);
    if (lane == 0) wcnt[wave][si] = c0 + (unsigned)__popcll(m1);
  }
  __syncthreads();
  if (t < NSLICE) {
    unsigned a = 0;
#pragma unroll
    for (int w = 0; w < 4; ++w) { woff[w][t] = a; a += wcnt[w][t]; }
    gbase[t] = atomicAdd(gcount + ((unsigned)t * NSTRIPE + stripe) * 16, a);
  }
  __syncthreads();
  unsigned off0 = gbase[slice0] + woff[wave][slice0] + rank0;
  if (off0 < STRIPE_CAP)
    __builtin_nontemporal_store(
        entry0, sstream + (size_t)(slice0 * NSTRIPE + stripe) * STRIPE_CAP + off0);
  unsigned off1 = gbase[slice1] + woff[wave][slice1] + rank1;
  if (off1 < STRIPE_CAP)
    __builtin_nontemporal_store(
        entry1, sstream + (size_t)(slice1 * NSTRIPE + stripe) * STRIPE_CAP + off1);
}

// ---- K3 (k_sub): 512 threads/block, 1024 blocks. LDS histogram re-bin +
// logit math. Scatter store PLAIN (R7 lesson: nt on 8B scatters = 6x write
// amplification). ----
__global__ __launch_bounds__(512) void k_sub(
    const ull* __restrict__ sstream, const unsigned* __restrict__ gcount,
    const float* __restrict__ a_src, const float* __restrict__ a_dst,
    ull* __restrict__ sub_stream, unsigned* __restrict__ sub_tail) {
  __shared__ unsigned hist[NSUB];
  __shared__ unsigned gb[NSUB];
  int t = threadIdx.x;
  int b = blockIdx.x;
  int slice = b & 7;
  int stripe = (b >> 3) & (NSTRIPE - 1);
  int chunk = b >> 8;                       // 0..3
  unsigned n = gcount[(slice * NSTRIPE + stripe) * 16];
  if (n > STRIPE_CAP) n = STRIPE_CAP;
  const ull* rb = sstream + (size_t)(slice * NSTRIPE + stripe) * STRIPE_CAP;
  unsigned start = (unsigned)chunk * K3_CHUNK;
  unsigned end = n < start + K3_CHUNK ? n : start + K3_CHUNK;
  if (t < NSUB) hist[t] = 0;
  __syncthreads();
  ull ent[4];
  unsigned bn[4];
  bool val[4];
#pragma unroll
  for (int u = 0; u < 4; ++u) {
    unsigned i = start + (unsigned)u * 512 + (unsigned)t;
    val[u] = (i < end);
    ent[u] = val[u] ? __builtin_nontemporal_load(rb + i) : 0ull;
  }
#pragma unroll
  for (int u = 0; u < 4; ++u) {
    unsigned dloc = (unsigned)(ent[u] >> 48);
    bn[u] = dloc / SUBW;
    if (val[u]) atomicAdd(&hist[bn[u]], 1u);
  }
  // prefetch gathers while histogram settles
  float asv[4], adv[4];
#pragma unroll
  for (int u = 0; u < 4; ++u) {
    unsigned src = (unsigned)(ent[u] & 0xFFFFFFFFu);
    unsigned dloc = (unsigned)(ent[u] >> 48);
    asv[u] = val[u] ? a_src[src] : 0.f;
    adv[u] = val[u] ? a_dst[slice * SLICE_W + dloc] : 0.f;
  }
  __syncthreads();
  if (t < NSUB && hist[t]) gb[t] = atomicAdd(sub_tail + ((slice * NSUB + t) * 16), hist[t]);
  __syncthreads();
  if (t < NSUB) hist[t] = 0;                // reuse as per-bin cursor
  __syncthreads();
#pragma unroll
  for (int u = 0; u < 4; ++u) {
    if (!val[u]) continue;
    unsigned src = (unsigned)(ent[u] & 0xFFFFFFFFu);
    float ae = __half2float(__ushort_as_half((unsigned short)((ent[u] >> 32) & 0xFFFFu)));
    unsigned dloc = (unsigned)(ent[u] >> 48);
    float al = asv[u] + adv[u] + ae;
    al = al >= 0.f ? al : NEG * al;
    float ee = expf(al);                    // shift-invariant softmax
    unsigned bq = __float_as_uint(ee);
    bq += 0x7fffu + ((bq >> 16) & 1u);      // RNE to bf16
    unsigned ee16 = (bq >> 16) & 0xFFFFu;
    unsigned aeh = (unsigned)((ent[u] >> 32) & 0xFFFFu);
    unsigned dlocs = dloc - bn[u] * SUBW;   // 0..97
    ull e2 = ((ull)dlocs << 56) | ((ull)ee16 << 40) | ((ull)aeh << 24) | (ull)src;
    unsigned r = atomicAdd(&hist[bn[u]], 1u);
    unsigned pos = gb[bn[u]] + r;
    if (pos < SUB_CAP)
      sub_stream[(size_t)(slice * NSUB + bn[u]) * SUB_CAP + pos] = e2;
  }
}

// ---- K4 (k_acc): Phase A in-LDS counting sort (1 LDS atomic/entry). Phase B
// 4 lanes/node, single-entry loop. ----
__global__ __launch_bounds__(512) void k_acc(
    const ull* __restrict__ sub_stream, const unsigned* __restrict__ sub_tail,
    const __hip_bfloat16* __restrict__ xbf, const float* __restrict__ W,
    const float* __restrict__ a_src, const float* __restrict__ a_dst,
    const float* __restrict__ bias, const float* __restrict__ lin_w,
    float* __restrict__ s_node) {
  __shared__ ull sorted[SUB_CAP];           // 16 KB
  __shared__ unsigned hist[NSUB];
  __shared__ unsigned pref[NSUB];
  __shared__ unsigned w0tot;
  __shared__ float sW[F_IN * HDIM];
  __shared__ float sb[HDIM], sl[HDIM];
  int t = threadIdx.x;
  int slice = blockIdx.x & 7;
  int bin = blockIdx.x >> 3;
  int nbase = slice * SLICE_W + bin * SUBW;
  int nnodes = SLICE_W - bin * SUBW; if (nnodes > SUBW) nnodes = SUBW;   // 98 or 54
  if (t < NSUB) hist[t] = 0;
  for (int i = t; i < F_IN * HDIM; i += 512) sW[i] = W[i];
  if (t < HDIM) { sb[t] = bias[t]; sl[t] = lin_w[t]; }
  __syncthreads();
  unsigned n = sub_tail[(slice * NSUB + bin) * 16];
  if (n > SUB_CAP) n = SUB_CAP;
  const ull* sp = sub_stream + (size_t)(slice * NSUB + bin) * SUB_CAP;
  // Phase A: count + rank
  ull ent[4];
  unsigned dl4[4], rk[4];
  bool val[4];
#pragma unroll
  for (int u = 0; u < 4; ++u) {
    unsigned i = (unsigned)u * 512 + (unsigned)t;
    val[u] = (i < n);
    ent[u] = val[u] ? sp[i] : 0ull;
  }
#pragma unroll
  for (int u = 0; u < 4; ++u) {
    dl4[u] = (unsigned)(ent[u] >> 56);
    if (val[u]) rk[u] = atomicAdd(&hist[dl4[u]], 1u);
  }
  __syncthreads();
  // exclusive prefix over 128 bins (waves 0,1 via shfl_up)
  if (t < NSUB) {
    unsigned v = hist[t];
    unsigned sc = v;
#pragma unroll
    for (int off = 1; off < 64; off <<= 1) {
      unsigned o = __shfl_up(sc, off);
      if ((t & 63) >= off) sc += o;
    }
    pref[t] = sc - v;                       // exclusive within wave
    if (t == 63) w0tot = sc;                // total of bins 0..63
  }
  __syncthreads();
  if (t >= 64 && t < NSUB) pref[t] += w0tot;
  __syncthreads();
  // scatter to sorted order
#pragma unroll
  for (int u = 0; u < 4; ++u)
    if (val[u]) sorted[pref[dl4[u]] + rk[u]] = ent[u];
  __syncthreads();
  // Phase B: 4 lanes/node, 128 groups (nnodes <= 98 -> one pass)
  int g = t >> 2, il = t & 3;
  if (g < nnodes) {
    int nl = g;
    int node = nbase + nl;
    unsigned start = pref[nl];
    unsigned cnt = hist[nl];
    float acc[F_IN];
#pragma unroll
    for (int j = 0; j < F_IN; ++j) acc[j] = 0.f;
    float denom = 0.f, sumae = 0.f;
    for (unsigned k = il; k < cnt; k += 4) {
      ull e2 = sorted[start + k];
      unsigned src = (unsigned)(e2 & 0xFFFFFFu);
      float ae = __half2float(__ushort_as_half((unsigned short)((e2 >> 24) & 0xFFFFu)));
      float ee = __uint_as_float(((unsigned)((e2 >> 40) & 0xFFFFu)) << 16);
      const uint4* xp = (const uint4*)(xbf + (size_t)src * F_IN);
      uint4 xa = xp[0], xb = xp[1];
      denom += ee;
      sumae += ae;
      float f0, f1;
      bf2(xa.x, f0, f1); acc[0] += ee * f0;  acc[1] += ee * f1;
      bf2(xa.y, f0, f1); acc[2] += ee * f0;  acc[3] += ee * f1;
      bf2(xa.z, f0, f1); acc[4] += ee * f0;  acc[5] += ee * f1;
      bf2(xa.w, f0, f1); acc[6] += ee * f0;  acc[7] += ee * f1;
      bf2(xb.x, f0, f1); acc[8] += ee * f0;  acc[9] += ee * f1;
      bf2(xb.y, f0, f1); acc[10] += ee * f0; acc[11] += ee * f1;
      bf2(xb.z, f0, f1); acc[12] += ee * f0; acc[13] += ee * f1;
      bf2(xb.w, f0, f1); acc[14] += ee * f0; acc[15] += ee * f1;
    }
    // reduce over the 4 lanes of this group (all lanes end with full sums)
#pragma unroll
    for (int off = 2; off > 0; off >>= 1) {
      denom += __shfl_xor(denom, off, 4);
      sumae += __shfl_xor(sumae, off, 4);
#pragma unroll
      for (int j = 0; j < F_IN; ++j) acc[j] += __shfl_xor(acc[j], off, 4);
    }
    // self-loop (fill_value='mean'): logit uses mean of incident a_e
    float all = a_src[node] + a_dst[node] + sumae / fmaxf((float)cnt, 1.f);
    all = all >= 0.f ? all : NEG * all;
    float eel = expf(all);
    denom += eel;
    {
      const uint4* xp = (const uint4*)(xbf + (size_t)node * F_IN);
      uint4 xa = xp[0], xb = xp[1];
      float f0, f1;
      bf2(xa.x, f0, f1); acc[0] += eel * f0;  acc[1] += eel * f1;
      bf2(xa.y, f0, f1); acc[2] += eel * f0;  acc[3] += eel * f1;
      bf2(xa.z, f0, f1); acc[4] += eel * f0;  acc[5] += eel * f1;
      bf2(xa.w, f0, f1); acc[6] += eel * f0;  acc[7] += eel * f1;
      bf2(xb.x, f0, f1); acc[8] += eel * f0;  acc[9] += eel * f1;
      bf2(xb.y, f0, f1); acc[10] += eel * f0; acc[11] += eel * f1;
      bf2(xb.z, f0, f1); acc[12] += eel * f0; acc[13] += eel * f1;
      bf2(xb.w, f0, f1); acc[14] += eel * f0; acc[15] += eel * f1;
    }
    float inv = 1.f / (denom + 1e-16f);
    // GEMV: lane il handles h = il + 4*stp, stp = 0..15
    float o = 0.f;
#pragma unroll
    for (int stp = 0; stp < 16; ++stp) {
      int h = il + stp * 4;
      float oh = 0.f;
#pragma unroll
      for (int j = 0; j < F_IN; ++j) oh += acc[j] * sW[j * HDIM + h];
      o += fmaxf(oh * inv + sb[h], 0.f) * sl[h];
    }
#pragma unroll
    for (int off = 2; off > 0; off >>= 1) o += __shfl_xor(o, off, 4);
    if (il == 0) s_node[node] = o;
  }
}

// ---- K5 (k_out): 4 edges/thread via int4/float4 — 8 independent s_node
// gathers in flight, quarter the loop overhead. ----
__global__ __launch_bounds__(256) void k_out(
    const int* __restrict__ ei, const float* __restrict__ s_node,
    const float* __restrict__ lin_b, float* __restrict__ out) {
  int e = (blockIdx.x * 256 + threadIdx.x) * 4;
  if (e >= N_EDGES) return;
  int4 ss = *(const int4*)(ei + e);
  int4 dd = *(const int4*)(ei + N_EDGES + e);
  float lb = lin_b[0];
  float s0 = s_node[ss.x], s1 = s_node[ss.y], s2 = s_node[ss.z], s3 = s_node[ss.w];
  float t0 = s_node[dd.x], t1 = s_node[dd.y], t2 = s_node[dd.z], t3 = s_node[dd.w];
  float4 r;
  r.x = 1.f / (1.f + expf(-(0.5f * (s0 + t0) + lb)));
  r.y = 1.f / (1.f + expf(-(0.5f * (s1 + t1) + lb)));
  r.z = 1.f / (1.f + expf(-(0.5f * (s2 + t2) + lb)));
  r.w = 1.f / (1.f + expf(-(0.5f * (s3 + t3) + lb)));
  *(float4*)(out + e) = r;
}

extern "C" void kernel_launch(void* const* d_in, const int* in_sizes, int n_in,
                              void* d_out, int out_size, void* d_ws, size_t ws_size,
                              hipStream_t stream) {
  const float* x        = (const float*)d_in[0];
  const float* edge_attr= (const float*)d_in[1];
  const float* W        = (const float*)d_in[2];
  const float* W_edge   = (const float*)d_in[3];
  const float* att_src  = (const float*)d_in[4];
  const float* att_dst  = (const float*)d_in[5];
  const float* att_edge = (const float*)d_in[6];
  const float* bias     = (const float*)d_in[7];
  const float* lin_w    = (const float*)d_in[8];
  const float* lin_b    = (const float*)d_in[9];
  const int*   ei       = (const int*)d_in[10];
  float* out = (float*)d_out;

  // workspace layout (16-B alignment preserved)
  char* base = (char*)d_ws;
  __hip_bfloat16* xbf = (__hip_bfloat16*)base;                      // 3.2 MB
  ull* sstream = (ull*)(base + (size_t)N_NODES * F_IN * 2);         // 256*7680*8 = 15.73 MB
  ull* sub_stream = sstream + (size_t)NSLICE * NSTRIPE * STRIPE_CAP; // 1024*2048*8 = 16.78 MB
  unsigned* gcount = (unsigned*)(sub_stream + (size_t)NSLICE * NSUB * SUB_CAP); // 16 KB (zeroed by k_node_h)
  unsigned* sub_tail = gcount + NSLICE * NSTRIPE * 16;              // 64 KB (zeroed by k_node_h)
  float* a_src  = (float*)(sub_tail + NSLICE * NSUB * 16);          // N
  float* a_dst  = a_src + N_NODES;                                  // N
  float* s_node = a_dst + N_NODES;                                  // N
  float* w_e    = s_node + N_NODES;                                 // 16
  // total ~ 37 MB

  int nb_node   = (N_NODES + 255) / 256;    // 391
  int nb_edge_p = N_EDGES / EPB;            // 3125, exact
  int nb_sub    = NSLICE * NSTRIPE * 4;     // 1024
  int nb_acc    = NSLICE * NSUB;            // 1024
  int nb_out    = (N_EDGES / 4 + 255) / 256; // 1563

  k_node_h  <<<nb_node, 256, 0, stream>>>(x, W, att_src, att_dst, W_edge,
                                          att_edge, w_e, gcount, xbf, a_src,
                                          a_dst);
  k_edge_pre<<<nb_edge_p, 256, 0, stream>>>(edge_attr, ei, w_e, sstream, gcount);
  k_sub     <<<nb_sub, 512, 0, stream>>>(sstream, gcount, a_src, a_dst,
                                         sub_stream, sub_tail);
  k_acc     <<<nb_acc, 512, 0, stream>>>(sub_stream, sub_tail, xbf, W,
                                         a_src, a_dst, bias, lin_w, s_node);
  k_out     <<<nb_out, 256, 0, stream>>>(ei, s_node, lin_b, out);
}